// Round 9
// baseline (1390.879 us; speedup 1.0000x reference)
//
#include <hip/hip_runtime.h>
#include <hip/hip_bf16.h>
#include <hip/hip_cooperative_groups.h>

namespace cg = cooperative_groups;

#define N_NODES 50000
#define N_EDGES 600000
#define HID 128
#define HEADS 8
#define OUTC 16
#define NEG_SLOPE 0.2f
#define BN_EPS 1e-5f

typedef __attribute__((ext_vector_type(8))) short short8;
typedef __attribute__((ext_vector_type(4))) float floatx4;

__device__ __forceinline__ float bf_lo(unsigned int v) { return __uint_as_float(v << 16); }
__device__ __forceinline__ float bf_hi(unsigned int v) { return __uint_as_float(v & 0xffff0000u); }

__device__ __forceinline__ short f2bfs(float v) {
    __hip_bfloat16 b = __float2bfloat16(v);
    return *reinterpret_cast<short*>(&b);
}

struct MegaParams {
    const float* x_in;
    const int* src;
    const int* dst;
    const float* W;
    const float* asrc;
    const float* adst;
    const float* gamma;
    const float* beta;
    float* out;
    __hip_bfloat16* Hb;
    float* XN;
    float* AS;
    float* AD;
    __hip_bfloat16* WT;
    __hip_bfloat16* WAT;
    float* STA;
    float* PAR;
    int* CNT;
    int* DEG;
    int* INC;
    int* RP;
    int* CUR;
    int* PRT;
    int* COL;
};

__global__ __launch_bounds__(256, 3) void k_mega(MegaParams P) {
    cg::grid_group grid = cg::this_grid();
    const int nb = gridDim.x;
    const int bid = blockIdx.x;
    const int tid = threadIdx.x;
    const int gthreads = nb * 256;
    const int gtid = bid * 256 + tid;

    __shared__ int s_scan[256];
    __shared__ float s_scale[128], s_shift[128];
    __shared__ float ssum[8][128], ssq[8][128];
    __shared__ int s_last;

    // ---- phase 0: zero DEG+CNT, weight prep (WT transpose->bf16, WAT fold) ----
    for (int i = gtid; i < N_NODES; i += gthreads) P.DEG[i] = 0;
    if (gtid < 3) P.CNT[gtid] = 0;
    for (int i = gtid; i < 3 * 16384 + 3 * 2048; i += gthreads) {
        if (i < 3 * 16384) {
            int l = i >> 14, r = i & 16383, n = r >> 7, k = r & 127;
            P.WT[i] = __float2bfloat16(P.W[l * 16384 + k * 128 + n]);
        } else {
            int q = i - 3 * 16384;
            int l = q >> 11, r = q & 2047, j = r >> 7, k = r & 127;
            const float* att = (j < 8) ? (P.asrc + l * 128 + j * 16)
                                       : (P.adst + l * 128 + (j - 8) * 16);
            const float* Wrow = P.W + l * 16384 + k * 128 + (j & 7) * 16;
            float sum = 0.f;
#pragma unroll
            for (int c = 0; c < 16; c++) sum += Wrow[c] * att[c];
            P.WAT[q] = __float2bfloat16(sum);
        }
    }
    grid.sync();

    // ---- phase 1: degree histogram ----
    for (int i = gtid; i < N_EDGES; i += gthreads) atomicAdd(&P.DEG[P.dst[i]], 1);
    grid.sync();

    // ---- phase 2a: block-local inclusive scans (196 virtual blocks x 256) ----
    const int NVB = (N_NODES + 255) / 256;   // 196
    for (int vb = bid; vb < NVB; vb += nb) {
        int i = vb * 256 + tid;
        int v = (i < N_NODES) ? P.DEG[i] : 0;
        s_scan[tid] = v;
        __syncthreads();
        for (int off = 1; off < 256; off <<= 1) {
            int t = (tid >= off) ? s_scan[tid - off] : 0;
            __syncthreads();
            s_scan[tid] += t;
            __syncthreads();
        }
        if (i < N_NODES) P.INC[i] = s_scan[tid];
        if (tid == 255) P.PRT[vb] = s_scan[255];
        __syncthreads();
    }
    grid.sync();

    // ---- phase 2b: block 0 exclusive-scans the 196 partials ----
    if (bid == 0) {
        int v = (tid < NVB) ? P.PRT[tid] : 0;
        s_scan[tid] = v;
        __syncthreads();
        for (int off = 1; off < 256; off <<= 1) {
            int t = (tid >= off) ? s_scan[tid - off] : 0;
            __syncthreads();
            s_scan[tid] += t;
            __syncthreads();
        }
        if (tid < NVB) P.PRT[tid] = s_scan[tid] - v;
    }
    grid.sync();

    // ---- phase 2c: RP/CUR ----
    for (int i = gtid; i < N_NODES; i += gthreads) {
        int rp = P.INC[i] - P.DEG[i] + P.PRT[i >> 8];
        P.RP[i] = rp;
        P.CUR[i] = rp;
    }
    if (gtid == 0) P.RP[N_NODES] = N_EDGES;
    grid.sync();

    // ---- phase 3: scatter edges into CSR ----
    for (int i = gtid; i < N_EDGES; i += gthreads) {
        int d = P.dst[i];
        int p = atomicAdd(&P.CUR[d], 1);
        P.COL[p] = P.src[i];
    }
    grid.sync();

    // ---- layer loop ----
    const int wave = tid >> 6, lane = tid & 63;
    const int m_lane = lane & 15, kq = lane >> 4;
    for (int l = 0; l < 3; l++) {
        // per-layer BN scale/shift for the input transform
        if (l > 0 && tid < 128) {
            const float* stats = P.STA + (l - 1) * 256;
            float invN = 1.0f / (float)N_NODES;
            float mu = stats[tid] * invN;
            float var = stats[128 + tid] * invN - mu * mu;
            float sc = rsqrtf(var + BN_EPS) * P.gamma[(l - 1) * 128 + tid];
            s_scale[tid] = sc;
            s_shift[tid] = P.beta[(l - 1) * 128 + tid] - mu * sc;
        }
        __syncthreads();

        // ---- GEMM + fused BN/ELU + fused alpha MFMA ----
        const float* Xf = (l == 0) ? P.x_in : P.XN;
        const short* Ws = (const short*)(P.WT + l * 16384);
        const short* Was = (const short*)(P.WAT + l * 2048);
        const int NT = (N_NODES + 63) / 64;   // 782
        for (int vt = bid; vt < NT; vt += nb) {
            int row0 = vt * 64 + wave * 16;
            floatx4 acc[8] = {};
            floatx4 acc_a = {};
            int r = row0 + m_lane;
            int rr = (r < N_NODES) ? r : 0;
            for (int c = 0; c < 4; c++) {
                const float4* xp = (const float4*)(Xf + (size_t)rr * 128 + c * 32 + kq * 8);
                float4 v0 = xp[0], v1 = xp[1];
                float vals[8] = {v0.x, v0.y, v0.z, v0.w, v1.x, v1.y, v1.z, v1.w};
                short8 a;
                if (l > 0) {
                    int ch0 = c * 32 + kq * 8;
#pragma unroll
                    for (int j = 0; j < 8; j++) {
                        float val = fmaf(vals[j], s_scale[ch0 + j], s_shift[ch0 + j]);
                        val = (val > 0.f) ? val : (__expf(val) - 1.0f);
                        a[j] = f2bfs(val);
                    }
                } else {
#pragma unroll
                    for (int j = 0; j < 8; j++) a[j] = f2bfs(vals[j]);
                }
                for (int t = 0; t < 8; t++) {
                    short8 b = *(const short8*)(Ws + (t * 16 + m_lane) * 128 + c * 32 + kq * 8);
                    acc[t] = __builtin_amdgcn_mfma_f32_16x16x32_bf16(a, b, acc[t], 0, 0, 0);
                }
                short8 bwa = *(const short8*)(Was + m_lane * 128 + c * 32 + kq * 8);
                acc_a = __builtin_amdgcn_mfma_f32_16x16x32_bf16(a, bwa, acc_a, 0, 0, 0);
            }
#pragma unroll
            for (int reg = 0; reg < 4; reg++) {
                int row = row0 + kq * 4 + reg;
                if (row >= N_NODES) continue;
#pragma unroll
                for (int t = 0; t < 8; t++)
                    P.Hb[(size_t)row * 128 + t * 16 + m_lane] = __float2bfloat16(acc[t][reg]);
                float av = acc_a[reg];
                if (m_lane < 8) P.AS[row * 8 + m_lane] = av;
                else            P.AD[row * 8 + (m_lane - 8)] = av;
            }
        }
        grid.sync();

        // ---- segment softmax + aggregation (one wave per node) ----
        const int NG = (N_NODES + 3) / 4;   // 12500
        const unsigned short* Hu = (const unsigned short*)P.Hb;
        for (int vg = bid; vg < NG; vg += nb) {
            int n = vg * 4 + wave;
            if (n >= N_NODES) continue;
            int e_l = lane >> 3, h = lane & 7;
            int p0 = P.RP[n], p1 = P.RP[n + 1];
            float ad = P.AD[n * 8 + h];
            float z = 0.f;
            float acc[16];
#pragma unroll
            for (int c = 0; c < 16; c++) acc[c] = 0.f;
            for (int p = p0 + e_l; p < p1; p += 8) {
                int s = P.COL[p];
                float e = P.AS[s * 8 + h] + ad;
                e = (e > 0.f) ? e : NEG_SLOPE * e;
                float w = __expf(e);   // |e| << 80, safe without max-subtract
                z += w;
                const uint4* hp = (const uint4*)(Hu + (size_t)s * 128 + h * 16);
                uint4 h0 = hp[0];
                uint4 h1 = hp[1];
                unsigned int ww[8] = {h0.x, h0.y, h0.z, h0.w, h1.x, h1.y, h1.z, h1.w};
#pragma unroll
                for (int j = 0; j < 8; j++) {
                    acc[2 * j]     += w * bf_lo(ww[j]);
                    acc[2 * j + 1] += w * bf_hi(ww[j]);
                }
            }
#pragma unroll
            for (int off = 8; off < 64; off <<= 1) {
                z += __shfl_xor(z, off, 64);
#pragma unroll
                for (int c = 0; c < 16; c++) acc[c] += __shfl_xor(acc[c], off, 64);
            }
            if (e_l == 0) {
                float inv = 1.0f / (z + 1e-16f);
                float4* op = (float4*)(P.XN + (size_t)n * 128 + h * 16);
#pragma unroll
                for (int q = 0; q < 4; q++)
                    op[q] = make_float4(acc[4 * q] * inv, acc[4 * q + 1] * inv,
                                        acc[4 * q + 2] * inv, acc[4 * q + 3] * inv);
            }
        }
        grid.sync();

        // ---- BN stats: blocks 0..255 partials + last-block reduce ----
        if (bid < 256) {
            int c4 = tid & 31, sub = tid >> 5;
            int g = bid * 8 + sub;
            float sx = 0.f, sy = 0.f, sz = 0.f, sw = 0.f;
            float qx = 0.f, qy = 0.f, qz = 0.f, qw = 0.f;
            for (int n = g; n < N_NODES; n += 2048) {
                float4 v = *(const float4*)(P.XN + (size_t)n * 128 + c4 * 4);
                sx += v.x; sy += v.y; sz += v.z; sw += v.w;
                qx += v.x * v.x; qy += v.y * v.y; qz += v.z * v.z; qw += v.w * v.w;
            }
            int c = c4 * 4;
            ssum[sub][c] = sx; ssum[sub][c + 1] = sy; ssum[sub][c + 2] = sz; ssum[sub][c + 3] = sw;
            ssq[sub][c] = qx;  ssq[sub][c + 1] = qy;  ssq[sub][c + 2] = qz;  ssq[sub][c + 3] = qw;
            __syncthreads();
            float total = 0.f;
            if (tid < 128) {
#pragma unroll
                for (int k = 0; k < 8; k++) total += ssum[k][tid];
            } else {
                int cc = tid - 128;
#pragma unroll
                for (int k = 0; k < 8; k++) total += ssq[k][cc];
            }
            P.PAR[bid * 256 + tid] = total;
            __threadfence();
            if (tid == 0) s_last = (atomicAdd(P.CNT + l, 1) == 255) ? 1 : 0;
            __syncthreads();
            if (s_last) {
                float s = 0.f;
#pragma unroll 8
                for (int b = 0; b < 256; b++) s += P.PAR[b * 256 + tid];
                P.STA[l * 256 + tid] = s;
            }
        }
        grid.sync();
    }

    // ---- final BN apply + ELU -> fp32 out ----
    {
        const float* stats = P.STA + 2 * 256;
        const float* gm = P.gamma + 2 * 128;
        const float* bt = P.beta + 2 * 128;
        float invN = 1.0f / (float)N_NODES;
        for (int i = gtid; i < N_NODES * 32; i += gthreads) {
            float4 v = *(const float4*)(P.XN + (size_t)i * 4);
            int c0 = (i * 4) & 127;
            float r[4] = {v.x, v.y, v.z, v.w};
#pragma unroll
            for (int j = 0; j < 4; j++) {
                int c = c0 + j;
                float mu = stats[c] * invN;
                float var = stats[128 + c] * invN - mu * mu;
                float sc = rsqrtf(var + BN_EPS) * gm[c];
                float val = (r[j] - mu) * sc + bt[c];
                val = (val > 0.f) ? val : (__expf(val) - 1.0f);
                r[j] = val;
            }
            *(float4*)(P.out + (size_t)i * 4) = make_float4(r[0], r[1], r[2], r[3]);
        }
    }
}

// ================= fallback multi-kernel path (proven round 8) =================
__global__ void k_hist_wtwa(const int* __restrict__ dst, int* __restrict__ deg, int e,
                            int nb_e, const float* __restrict__ W,
                            const float* __restrict__ asrc, const float* __restrict__ adst,
                            __hip_bfloat16* __restrict__ Wt, __hip_bfloat16* __restrict__ WAT) {
    if (blockIdx.x < (unsigned)nb_e) {
        int i = blockIdx.x * 256 + threadIdx.x;
        if (i < e) atomicAdd(&deg[dst[i]], 1);
    } else {
        int i = (blockIdx.x - nb_e) * 256 + threadIdx.x;
        if (i < 3 * 16384) {
            int l = i >> 14, r = i & 16383, n = r >> 7, k = r & 127;
            Wt[i] = __float2bfloat16(W[l * 16384 + k * 128 + n]);
        } else if (i < 3 * 16384 + 3 * 2048) {
            int q = i - 3 * 16384;
            int l = q >> 11, r = q & 2047, j = r >> 7, k = r & 127;
            const float* att = (j < 8) ? (asrc + l * 128 + j * 16) : (adst + l * 128 + (j - 8) * 16);
            const float* Wrow = W + l * 16384 + k * 128 + (j & 7) * 16;
            float sum = 0.f;
#pragma unroll
            for (int c = 0; c < 16; c++) sum += Wrow[c] * att[c];
            WAT[q] = __float2bfloat16(sum);
        }
    }
}

__global__ void k_scan1(const int* __restrict__ deg, int* __restrict__ incl,
                        int* __restrict__ partials, int n) {
    __shared__ int sh[512];
    int i = blockIdx.x * 512 + threadIdx.x;
    int v = (i < n) ? deg[i] : 0;
    sh[threadIdx.x] = v;
    __syncthreads();
    for (int off = 1; off < 512; off <<= 1) {
        int t = (threadIdx.x >= off) ? sh[threadIdx.x - off] : 0;
        __syncthreads();
        sh[threadIdx.x] += t;
        __syncthreads();
    }
    if (i < n) incl[i] = sh[threadIdx.x];
    if (threadIdx.x == 511) partials[blockIdx.x] = sh[511];
}

__global__ void k_scan2(int* __restrict__ partials, int nb) {
    __shared__ int sh[128];
    int v = (threadIdx.x < nb) ? partials[threadIdx.x] : 0;
    sh[threadIdx.x] = v;
    __syncthreads();
    for (int off = 1; off < 128; off <<= 1) {
        int t = (threadIdx.x >= off) ? sh[threadIdx.x - off] : 0;
        __syncthreads();
        sh[threadIdx.x] += t;
        __syncthreads();
    }
    if (threadIdx.x < nb) partials[threadIdx.x] = sh[threadIdx.x] - v;
}

__global__ void k_scan3(const int* __restrict__ deg, const int* __restrict__ incl,
                        const int* __restrict__ partials, int* __restrict__ row_ptr,
                        int* __restrict__ cursor, int n, int e_total) {
    int i = blockIdx.x * 512 + threadIdx.x;
    if (i < n) {
        int rp = incl[i] - deg[i] + partials[blockIdx.x];
        row_ptr[i] = rp;
        cursor[i] = rp;
    }
    if (i == 0) row_ptr[n] = e_total;
}

__global__ void k_scatter(const int* __restrict__ src, const int* __restrict__ dst,
                          int* __restrict__ cursor, int* __restrict__ col_src, int e) {
    int i = blockIdx.x * 256 + threadIdx.x;
    if (i < e) {
        int d = dst[i];
        int p = atomicAdd(&cursor[d], 1);
        col_src[p] = src[i];
    }
}

__global__ __launch_bounds__(256) void k_gemm(const float* __restrict__ Xf,
                                              const float* __restrict__ stats,
                                              const float* __restrict__ gamma,
                                              const float* __restrict__ beta,
                                              const __hip_bfloat16* __restrict__ Wt,
                                              const __hip_bfloat16* __restrict__ WAT,
                                              __hip_bfloat16* __restrict__ Hb,
                                              float* __restrict__ AS, float* __restrict__ AD,
                                              int n_nodes, int apply_bn) {
    __shared__ float s_scale[128], s_shift[128];
    if (apply_bn && threadIdx.x < 128) {
        int c = threadIdx.x;
        float invN = 1.0f / (float)N_NODES;
        float mu = stats[c] * invN;
        float var = stats[128 + c] * invN - mu * mu;
        float sc = rsqrtf(var + BN_EPS) * gamma[c];
        s_scale[c] = sc;
        s_shift[c] = beta[c] - mu * sc;
    }
    __syncthreads();
    int wave = threadIdx.x >> 6, lane = threadIdx.x & 63;
    int row0 = blockIdx.x * 64 + wave * 16;
    int m_lane = lane & 15, kq = lane >> 4;
    floatx4 acc[8] = {};
    floatx4 acc_a = {};
    const short* Ws = (const short*)Wt;
    const short* Was = (const short*)WAT;
    int r = row0 + m_lane;
    int rr = (r < n_nodes) ? r : 0;
    for (int c = 0; c < 4; c++) {
        const float4* xp = (const float4*)(Xf + (size_t)rr * 128 + c * 32 + kq * 8);
        float4 v0 = xp[0], v1 = xp[1];
        float vals[8] = {v0.x, v0.y, v0.z, v0.w, v1.x, v1.y, v1.z, v1.w};
        short8 a;
        if (apply_bn) {
            int ch0 = c * 32 + kq * 8;
#pragma unroll
            for (int j = 0; j < 8; j++) {
                float val = fmaf(vals[j], s_scale[ch0 + j], s_shift[ch0 + j]);
                val = (val > 0.f) ? val : (__expf(val) - 1.0f);
                a[j] = f2bfs(val);
            }
        } else {
#pragma unroll
            for (int j = 0; j < 8; j++) a[j] = f2bfs(vals[j]);
        }
        for (int t = 0; t < 8; t++) {
            short8 b = *(const short8*)(Ws + (t * 16 + m_lane) * 128 + c * 32 + kq * 8);
            acc[t] = __builtin_amdgcn_mfma_f32_16x16x32_bf16(a, b, acc[t], 0, 0, 0);
        }
        short8 bwa = *(const short8*)(Was + m_lane * 128 + c * 32 + kq * 8);
        acc_a = __builtin_amdgcn_mfma_f32_16x16x32_bf16(a, bwa, acc_a, 0, 0, 0);
    }
#pragma unroll
    for (int reg = 0; reg < 4; reg++) {
        int row = row0 + kq * 4 + reg;
        if (row >= n_nodes) continue;
#pragma unroll
        for (int t = 0; t < 8; t++)
            Hb[(size_t)row * 128 + t * 16 + m_lane] = __float2bfloat16(acc[t][reg]);
        float av = acc_a[reg];
        if (m_lane < 8) AS[row * 8 + m_lane] = av;
        else            AD[row * 8 + (m_lane - 8)] = av;
    }
}

__global__ __launch_bounds__(256) void k_agg(const int* __restrict__ RP,
                                             const int* __restrict__ COL,
                                             const float* __restrict__ AS,
                                             const float* __restrict__ AD,
                                             const __hip_bfloat16* __restrict__ Hb,
                                             float* __restrict__ out, int n_nodes) {
    int wave = threadIdx.x >> 6, lane = threadIdx.x & 63;
    int n = blockIdx.x * 4 + wave;
    if (n >= n_nodes) return;
    int e_l = lane >> 3, h = lane & 7;
    int p0 = RP[n], p1 = RP[n + 1];
    float ad = AD[n * 8 + h];
    float z = 0.f;
    float acc[16];
#pragma unroll
    for (int c = 0; c < 16; c++) acc[c] = 0.f;
    const unsigned short* Hu = (const unsigned short*)Hb;
    for (int p = p0 + e_l; p < p1; p += 8) {
        int s = COL[p];
        float e = AS[s * 8 + h] + ad;
        e = (e > 0.f) ? e : NEG_SLOPE * e;
        float w = __expf(e);
        z += w;
        const uint4* hp = (const uint4*)(Hu + (size_t)s * 128 + h * 16);
        uint4 h0 = hp[0];
        uint4 h1 = hp[1];
        unsigned int ww[8] = {h0.x, h0.y, h0.z, h0.w, h1.x, h1.y, h1.z, h1.w};
#pragma unroll
        for (int j = 0; j < 8; j++) {
            acc[2 * j]     += w * bf_lo(ww[j]);
            acc[2 * j + 1] += w * bf_hi(ww[j]);
        }
    }
#pragma unroll
    for (int off = 8; off < 64; off <<= 1) {
        z += __shfl_xor(z, off, 64);
#pragma unroll
        for (int c = 0; c < 16; c++) acc[c] += __shfl_xor(acc[c], off, 64);
    }
    if (e_l == 0) {
        float inv = 1.0f / (z + 1e-16f);
        float4* op = (float4*)(out + (size_t)n * 128 + h * 16);
#pragma unroll
        for (int q = 0; q < 4; q++)
            op[q] = make_float4(acc[4 * q] * inv, acc[4 * q + 1] * inv,
                                acc[4 * q + 2] * inv, acc[4 * q + 3] * inv);
    }
}

__global__ __launch_bounds__(256) void k_bnstats(const float* __restrict__ x,
                                                 float* __restrict__ partials,
                                                 float* __restrict__ stats,
                                                 int* __restrict__ counter, int n_nodes) {
    int tid = threadIdx.x;
    int c4 = tid & 31, sub = tid >> 5;
    int g = blockIdx.x * 8 + sub;
    float sx = 0.f, sy = 0.f, sz = 0.f, sw = 0.f;
    float qx = 0.f, qy = 0.f, qz = 0.f, qw = 0.f;
    for (int n = g; n < n_nodes; n += 2048) {
        float4 v = *(const float4*)(x + (size_t)n * 128 + c4 * 4);
        sx += v.x; sy += v.y; sz += v.z; sw += v.w;
        qx += v.x * v.x; qy += v.y * v.y; qz += v.z * v.z; qw += v.w * v.w;
    }
    __shared__ float ssum[8][128];
    __shared__ float ssq[8][128];
    int c = c4 * 4;
    ssum[sub][c] = sx; ssum[sub][c + 1] = sy; ssum[sub][c + 2] = sz; ssum[sub][c + 3] = sw;
    ssq[sub][c] = qx;  ssq[sub][c + 1] = qy;  ssq[sub][c + 2] = qz;  ssq[sub][c + 3] = qw;
    __syncthreads();
    float total = 0.f;
    if (tid < 128) {
#pragma unroll
        for (int k = 0; k < 8; k++) total += ssum[k][tid];
    } else {
        int cc = tid - 128;
#pragma unroll
        for (int k = 0; k < 8; k++) total += ssq[k][cc];
    }
    partials[blockIdx.x * 256 + tid] = total;
    __threadfence();
    __shared__ int s_last;
    if (tid == 0) s_last = (atomicAdd(counter, 1) == 255) ? 1 : 0;
    __syncthreads();
    if (s_last) {
        float s = 0.f;
#pragma unroll 8
        for (int b = 0; b < 256; b++) s += partials[b * 256 + tid];
        stats[tid] = s;
    }
}

__global__ void k_bnapply(const float* __restrict__ x, const float* __restrict__ stats,
                          const float* __restrict__ gamma, const float* __restrict__ beta,
                          float* __restrict__ outf, int n_nodes) {
    int i = blockIdx.x * 256 + threadIdx.x;
    if (i >= n_nodes * 32) return;
    float4 v = *(const float4*)(x + (size_t)i * 4);
    int c0 = (i * 4) & 127;
    float r[4] = {v.x, v.y, v.z, v.w};
    float invN = 1.0f / (float)N_NODES;
#pragma unroll
    for (int j = 0; j < 4; j++) {
        int c = c0 + j;
        float mu = stats[c] * invN;
        float var = stats[128 + c] * invN - mu * mu;
        float sc = rsqrtf(var + BN_EPS) * gamma[c];
        float val = (r[j] - mu) * sc + beta[c];
        val = (val > 0.f) ? val : (__expf(val) - 1.0f);
        r[j] = val;
    }
    *(float4*)(outf + (size_t)i * 4) = make_float4(r[0], r[1], r[2], r[3]);
}

extern "C" void kernel_launch(void* const* d_in, const int* in_sizes, int n_in,
                              void* d_out, int out_size, void* d_ws, size_t ws_size,
                              hipStream_t stream) {
    const float* x_in   = (const float*)d_in[0];
    const int*   eidx   = (const int*)d_in[1];
    const float* W      = (const float*)d_in[2];
    const float* attsrc = (const float*)d_in[3];
    const float* attdst = (const float*)d_in[4];
    // d_in[5] = bias — exactly cancelled by BatchNorm; unused.
    const float* gamma  = (const float*)d_in[6];
    const float* beta   = (const float*)d_in[7];
    float* out = (float*)d_out;

    const int N = N_NODES, E = N_EDGES;
    const int* src = eidx;
    const int* dst = eidx + E;

    char* base = (char*)d_ws;
    size_t off = 0;
    auto carve = [&](size_t bytes) -> char* {
        char* p = base + off;
        off += (bytes + 255) & ~(size_t)255;
        return p;
    };
    __hip_bfloat16* Hb  = (__hip_bfloat16*)carve((size_t)N * HID * 2);
    float*          XN  = (float*)carve((size_t)N * HID * 4);
    float*          AS  = (float*)carve((size_t)N * HEADS * 4);
    float*          AD  = (float*)carve((size_t)N * HEADS * 4);
    __hip_bfloat16* WT  = (__hip_bfloat16*)carve((size_t)3 * HID * HID * 2);
    __hip_bfloat16* WAT = (__hip_bfloat16*)carve((size_t)3 * 16 * HID * 2);
    float*          STA = (float*)carve(3 * 256 * 4);
    float*          PAR = (float*)carve(256 * 256 * 4);
    int*            CNT = (int*)carve(256);
    int*            DEG = (int*)carve((size_t)N * 4);
    int*            INC = (int*)carve((size_t)N * 4);
    int*            RP  = (int*)carve((size_t)(N + 1) * 4);
    int*            CUR = (int*)carve((size_t)N * 4);
    int*            PRT = (int*)carve(1024 * 4);
    int*            COL = (int*)carve((size_t)E * 4);

    // ---- try single cooperative mega-kernel ----
    MegaParams P = { x_in, src, dst, W, attsrc, attdst, gamma, beta, out,
                     Hb, XN, AS, AD, WT, WAT, STA, PAR, CNT, DEG, INC, RP, CUR, PRT, COL };
    int perCU = 0;
    hipError_t qerr = hipOccupancyMaxActiveBlocksPerMultiprocessor(
        &perCU, reinterpret_cast<const void*>(k_mega), 256, 0);
    int grid = (qerr == hipSuccess && perCU > 0) ? perCU * 256 : 768;
    if (grid > 2048) grid = 2048;
    void* args[] = { (void*)&P };
    hipError_t lerr = hipLaunchCooperativeKernel(reinterpret_cast<const void*>(k_mega),
                                                 dim3(grid), dim3(256), args, 0, stream);
    if (lerr == hipSuccess) return;

    // ---- fallback: proven round-8 multi-kernel path ----
    const int NB_E  = (E + 255) / 256;
    const int NB_SC = (N + 511) / 512;
    const int NB_W  = (3 * 16384 + 3 * 2048 + 255) / 256;

    (void)hipMemsetAsync(CNT, 0, 256 + (size_t)N * 4, stream);
    k_hist_wtwa<<<NB_E + NB_W, 256, 0, stream>>>(dst, DEG, E, NB_E, W, attsrc, attdst, WT, WAT);
    k_scan1<<<NB_SC, 512, 0, stream>>>(DEG, INC, PRT, N);
    k_scan2<<<1, 128, 0, stream>>>(PRT, NB_SC);
    k_scan3<<<NB_SC, 512, 0, stream>>>(DEG, INC, PRT, RP, CUR, N, E);
    k_scatter<<<NB_E, 256, 0, stream>>>(src, dst, CUR, COL, E);

    for (int l = 0; l < 3; l++) {
        const float* Xf = (l == 0) ? x_in : XN;
        const float* st = (l == 0) ? nullptr : (STA + (l - 1) * 256);
        const float* gm = gamma + (l - 1) * 128;
        const float* bt = beta + (l - 1) * 128;
        k_gemm<<<(N + 63) / 64, 256, 0, stream>>>(Xf, st, gm, bt,
                                                  WT + l * 16384, WAT + l * 2048,
                                                  Hb, AS, AD, N, (l == 0) ? 0 : 1);
        k_agg<<<(N + 3) / 4, 256, 0, stream>>>(RP, COL, AS, AD, Hb, XN, N);
        k_bnstats<<<256, 256, 0, stream>>>(XN, PAR, STA + l * 256, CNT + l, N);
    }
    k_bnapply<<<(N * 32 + 255) / 256, 256, 0, stream>>>(XN, STA + 2 * 256,
                                                        gamma + 2 * 128, beta + 2 * 128, out, N);
}

// Round 10
// 737.150 us; speedup vs baseline: 1.8868x; 1.8868x over previous
//
#include <hip/hip_runtime.h>
#include <hip/hip_bf16.h>

#define N_NODES 50000
#define N_EDGES 600000
#define HID 128
#define HEADS 8
#define OUTC 16
#define NEG_SLOPE 0.2f
#define BN_EPS 1e-5f

typedef __attribute__((ext_vector_type(8))) short short8;
typedef __attribute__((ext_vector_type(4))) float floatx4;

__device__ __forceinline__ float bf_lo(unsigned int v) { return __uint_as_float(v << 16); }
__device__ __forceinline__ float bf_hi(unsigned int v) { return __uint_as_float(v & 0xffff0000u); }
__device__ __forceinline__ float bf1(unsigned short v) { return __uint_as_float((unsigned int)v << 16); }

__device__ __forceinline__ short f2bfs(float v) {
    __hip_bfloat16 b = __float2bfloat16(v);
    return *reinterpret_cast<short*>(&b);
}

// ---- hist (blocks < nb_e) + weight prep (blocks >= nb_e), independent work ----
__global__ void k_hist_wtwa(const int* __restrict__ dst, int* __restrict__ deg, int e,
                            int nb_e, const float* __restrict__ W,
                            const float* __restrict__ asrc, const float* __restrict__ adst,
                            __hip_bfloat16* __restrict__ Wt, __hip_bfloat16* __restrict__ WAT) {
    if (blockIdx.x < (unsigned)nb_e) {
        int i = blockIdx.x * 256 + threadIdx.x;
        if (i < e) atomicAdd(&deg[dst[i]], 1);
    } else {
        int i = (blockIdx.x - nb_e) * 256 + threadIdx.x;   // 55296 total
        if (i < 3 * 16384) {
            int l = i >> 14, r = i & 16383, n = r >> 7, k = r & 127;
            Wt[i] = __float2bfloat16(W[l * 16384 + k * 128 + n]);
        } else if (i < 3 * 16384 + 3 * 2048) {
            int q = i - 3 * 16384;
            int l = q >> 11, r = q & 2047, j = r >> 7, k = r & 127;
            const float* att = (j < 8) ? (asrc + l * 128 + j * 16) : (adst + l * 128 + (j - 8) * 16);
            const float* Wrow = W + l * 16384 + k * 128 + (j & 7) * 16;
            float sum = 0.f;
#pragma unroll
            for (int c = 0; c < 16; c++) sum += Wrow[c] * att[c];
            WAT[q] = __float2bfloat16(sum);
        }
    }
}

// ---------------- 3-kernel parallel scan (proven) ----------------
__global__ void k_scan1(const int* __restrict__ deg, int* __restrict__ incl,
                        int* __restrict__ partials, int n) {
    __shared__ int sh[512];
    int i = blockIdx.x * 512 + threadIdx.x;
    int v = (i < n) ? deg[i] : 0;
    sh[threadIdx.x] = v;
    __syncthreads();
    for (int off = 1; off < 512; off <<= 1) {
        int t = (threadIdx.x >= off) ? sh[threadIdx.x - off] : 0;
        __syncthreads();
        sh[threadIdx.x] += t;
        __syncthreads();
    }
    if (i < n) incl[i] = sh[threadIdx.x];
    if (threadIdx.x == 511) partials[blockIdx.x] = sh[511];
}

__global__ void k_scan2(int* __restrict__ partials, int nb) {
    __shared__ int sh[128];
    int v = (threadIdx.x < nb) ? partials[threadIdx.x] : 0;
    sh[threadIdx.x] = v;
    __syncthreads();
    for (int off = 1; off < 128; off <<= 1) {
        int t = (threadIdx.x >= off) ? sh[threadIdx.x - off] : 0;
        __syncthreads();
        sh[threadIdx.x] += t;
        __syncthreads();
    }
    if (threadIdx.x < nb) partials[threadIdx.x] = sh[threadIdx.x] - v;  // exclusive
}

__global__ void k_scan3(const int* __restrict__ deg, const int* __restrict__ incl,
                        const int* __restrict__ partials, int* __restrict__ row_ptr,
                        int* __restrict__ cursor, int n, int e_total) {
    int i = blockIdx.x * 512 + threadIdx.x;
    if (i < n) {
        int rp = incl[i] - deg[i] + partials[blockIdx.x];
        row_ptr[i] = rp;
        cursor[i] = rp;
    }
    if (i == 0) row_ptr[n] = e_total;
}

__global__ void k_scatter(const int* __restrict__ src, const int* __restrict__ dst,
                          int* __restrict__ cursor, int* __restrict__ col_src, int e) {
    int i = blockIdx.x * 256 + threadIdx.x;
    if (i < e) {
        int d = dst[i];
        int p = atomicAdd(&cursor[d], 1);
        col_src[p] = src[i];
    }
}

// ---- GEMM + fused BN/ELU on input + fused alpha via extra MFMA ----
// Outputs HEAD-MAJOR: Hh[h][n][16] bf16; AS/AD[h][n] fp32.
__global__ __launch_bounds__(256) void k_gemm(const float* __restrict__ Xf,
                                              const float* __restrict__ stats,   // null if !apply_bn
                                              const float* __restrict__ gamma,
                                              const float* __restrict__ beta,
                                              const __hip_bfloat16* __restrict__ Wt,
                                              const __hip_bfloat16* __restrict__ WAT,
                                              __hip_bfloat16* __restrict__ Hh,
                                              float* __restrict__ AS, float* __restrict__ AD,
                                              int n_nodes, int apply_bn) {
    __shared__ float s_scale[128], s_shift[128];
    if (apply_bn && threadIdx.x < 128) {
        int c = threadIdx.x;
        float invN = 1.0f / (float)N_NODES;
        float mu = stats[c] * invN;
        float var = stats[128 + c] * invN - mu * mu;
        float sc = rsqrtf(var + BN_EPS) * gamma[c];
        s_scale[c] = sc;
        s_shift[c] = beta[c] - mu * sc;
    }
    __syncthreads();

    int wave = threadIdx.x >> 6, lane = threadIdx.x & 63;
    int row0 = blockIdx.x * 64 + wave * 16;
    int m_lane = lane & 15, kq = lane >> 4;
    floatx4 acc[8] = {};
    floatx4 acc_a = {};
    const short* Ws = (const short*)Wt;
    const short* Was = (const short*)WAT;
    int r = row0 + m_lane;
    int rr = (r < n_nodes) ? r : 0;
    for (int c = 0; c < 4; c++) {
        const float4* xp = (const float4*)(Xf + (size_t)rr * 128 + c * 32 + kq * 8);
        float4 v0 = xp[0], v1 = xp[1];
        float vals[8] = {v0.x, v0.y, v0.z, v0.w, v1.x, v1.y, v1.z, v1.w};
        short8 a;
        if (apply_bn) {
            int ch0 = c * 32 + kq * 8;
#pragma unroll
            for (int j = 0; j < 8; j++) {
                float val = fmaf(vals[j], s_scale[ch0 + j], s_shift[ch0 + j]);
                val = (val > 0.f) ? val : (__expf(val) - 1.0f);
                a[j] = f2bfs(val);
            }
        } else {
#pragma unroll
            for (int j = 0; j < 8; j++) a[j] = f2bfs(vals[j]);
        }
        for (int t = 0; t < 8; t++) {
            short8 b = *(const short8*)(Ws + (t * 16 + m_lane) * 128 + c * 32 + kq * 8);
            acc[t] = __builtin_amdgcn_mfma_f32_16x16x32_bf16(a, b, acc[t], 0, 0, 0);
        }
        short8 bwa = *(const short8*)(Was + m_lane * 128 + c * 32 + kq * 8);
        acc_a = __builtin_amdgcn_mfma_f32_16x16x32_bf16(a, bwa, acc_a, 0, 0, 0);
    }
#pragma unroll
    for (int reg = 0; reg < 4; reg++) {
        int row = row0 + kq * 4 + reg;
        if (row >= n_nodes) continue;
#pragma unroll
        for (int t = 0; t < 8; t++)
            Hh[((size_t)t * n_nodes + row) * 16 + m_lane] = __float2bfloat16(acc[t][reg]);
        float av = acc_a[reg];
        if (m_lane < 8) AS[(size_t)m_lane * n_nodes + row] = av;
        else            AD[(size_t)(m_lane - 8) * n_nodes + row] = av;
    }
}

// ---- head-phased segment softmax + aggregation ----
// Grid = 8 heads x 6250 groups (head-major block order -> concurrent blocks share one
// head's 1.6MB slab, L2-resident). Wave = (node, head); lane = edge_slot(4) x channel(16).
__global__ __launch_bounds__(256) void k_agg(const int* __restrict__ RP,
                                             const int* __restrict__ COL,
                                             const float* __restrict__ AS,
                                             const float* __restrict__ AD,
                                             const __hip_bfloat16* __restrict__ Hh,
                                             float* __restrict__ out, int n_nodes) {
    int wave = threadIdx.x >> 6, lane = threadIdx.x & 63;
    int h = blockIdx.x / 6250;
    int g = blockIdx.x % 6250;
    int e_l = lane >> 4, c = lane & 15;
    const unsigned short* Hu = (const unsigned short*)(Hh + (size_t)h * n_nodes * 16);
    const float* ASh = AS + (size_t)h * n_nodes;
    const float* ADh = AD + (size_t)h * n_nodes;
#pragma unroll
    for (int nn = 0; nn < 2; nn++) {
        int n = g * 8 + wave * 2 + nn;
        if (n >= n_nodes) continue;
        int p0 = RP[n], p1 = RP[n + 1];
        float ad = ADh[n];
        float z = 0.f, acc = 0.f;
        for (int p = p0 + e_l; p < p1; p += 4) {
            int s = COL[p];
            float e = ASh[s] + ad;
            e = (e > 0.f) ? e : NEG_SLOPE * e;
            float w = __expf(e);   // |e| << 80, safe without max-subtract
            z += w;
            acc += w * bf1(Hu[(size_t)s * 16 + c]);
        }
        // butterfly over the 4 edge slots (lane bits 4..5)
#pragma unroll
        for (int off = 16; off < 64; off <<= 1) {
            z += __shfl_xor(z, off, 64);
            acc += __shfl_xor(acc, off, 64);
        }
        if (e_l == 0)
            out[(size_t)n * 128 + h * 16 + c] = acc / (z + 1e-16f);
    }
}

// ---- BN stats: per-block partials + last-block reduce (single kernel, grid=256) ----
__global__ __launch_bounds__(256) void k_bnstats(const float* __restrict__ x,
                                                 float* __restrict__ partials,
                                                 float* __restrict__ stats,
                                                 int* __restrict__ counter, int n_nodes) {
    int tid = threadIdx.x;
    int c4 = tid & 31, sub = tid >> 5;          // 8 row-groups per block
    int g = blockIdx.x * 8 + sub;               // 2048 row-groups total
    float sx = 0.f, sy = 0.f, sz = 0.f, sw = 0.f;
    float qx = 0.f, qy = 0.f, qz = 0.f, qw = 0.f;
    for (int n = g; n < n_nodes; n += 2048) {
        float4 v = *(const float4*)(x + (size_t)n * 128 + c4 * 4);
        sx += v.x; sy += v.y; sz += v.z; sw += v.w;
        qx += v.x * v.x; qy += v.y * v.y; qz += v.z * v.z; qw += v.w * v.w;
    }
    __shared__ float ssum[8][128];
    __shared__ float ssq[8][128];
    int c = c4 * 4;
    ssum[sub][c] = sx; ssum[sub][c + 1] = sy; ssum[sub][c + 2] = sz; ssum[sub][c + 3] = sw;
    ssq[sub][c] = qx;  ssq[sub][c + 1] = qy;  ssq[sub][c + 2] = qz;  ssq[sub][c + 3] = qw;
    __syncthreads();
    float total = 0.f;
    if (tid < 128) {
#pragma unroll
        for (int k = 0; k < 8; k++) total += ssum[k][tid];
    } else {
        int cc = tid - 128;
#pragma unroll
        for (int k = 0; k < 8; k++) total += ssq[k][cc];
    }
    partials[blockIdx.x * 256 + tid] = total;
    __threadfence();
    __shared__ int s_last;
    if (tid == 0) s_last = (atomicAdd(counter, 1) == 255) ? 1 : 0;
    __syncthreads();
    if (s_last) {
        float s = 0.f;
#pragma unroll 8
        for (int b = 0; b < 256; b++) s += partials[b * 256 + tid];
        stats[tid] = s;
    }
}

// ---------------- final BN apply + ELU -> fp32 out ----------------
__global__ void k_bnapply(const float* __restrict__ x, const float* __restrict__ stats,
                          const float* __restrict__ gamma, const float* __restrict__ beta,
                          float* __restrict__ outf, int n_nodes) {
    int i = blockIdx.x * 256 + threadIdx.x;
    if (i >= n_nodes * 32) return;
    float4 v = *(const float4*)(x + (size_t)i * 4);
    int c0 = (i * 4) & 127;
    float r[4] = {v.x, v.y, v.z, v.w};
    float invN = 1.0f / (float)N_NODES;
#pragma unroll
    for (int j = 0; j < 4; j++) {
        int c = c0 + j;
        float mu = stats[c] * invN;
        float var = stats[128 + c] * invN - mu * mu;
        float sc = rsqrtf(var + BN_EPS) * gamma[c];
        float val = (r[j] - mu) * sc + beta[c];
        val = (val > 0.f) ? val : (__expf(val) - 1.0f);
        r[j] = val;
    }
    *(float4*)(outf + (size_t)i * 4) = make_float4(r[0], r[1], r[2], r[3]);
}

extern "C" void kernel_launch(void* const* d_in, const int* in_sizes, int n_in,
                              void* d_out, int out_size, void* d_ws, size_t ws_size,
                              hipStream_t stream) {
    const float* x_in   = (const float*)d_in[0];
    const int*   eidx   = (const int*)d_in[1];
    const float* W      = (const float*)d_in[2];
    const float* attsrc = (const float*)d_in[3];
    const float* attdst = (const float*)d_in[4];
    // d_in[5] = bias — exactly cancelled by BatchNorm; unused.
    const float* gamma  = (const float*)d_in[6];
    const float* beta   = (const float*)d_in[7];
    float* out = (float*)d_out;

    const int N = N_NODES, E = N_EDGES;
    const int* src = eidx;
    const int* dst = eidx + E;

    char* base = (char*)d_ws;
    size_t off = 0;
    auto carve = [&](size_t bytes) -> char* {
        char* p = base + off;
        off += (bytes + 255) & ~(size_t)255;
        return p;
    };
    __hip_bfloat16* Hh  = (__hip_bfloat16*)carve((size_t)N * HID * 2);  // head-major
    float*          XN  = (float*)carve((size_t)N * HID * 4);
    float*          AS  = (float*)carve((size_t)N * HEADS * 4);        // head-major
    float*          AD  = (float*)carve((size_t)N * HEADS * 4);        // head-major
    __hip_bfloat16* WT  = (__hip_bfloat16*)carve((size_t)3 * HID * HID * 2);
    __hip_bfloat16* WAT = (__hip_bfloat16*)carve((size_t)3 * 16 * HID * 2);
    float*          STA = (float*)carve(3 * 256 * 4);
    float*          PAR = (float*)carve(256 * 256 * 4);
    int*            CNT = (int*)carve(256);                   // 3 counters (zeroed w/ DEG)
    int*            DEG = (int*)carve((size_t)N * 4);         // adjacent to CNT
    int*            INC = (int*)carve((size_t)N * 4);
    int*            RP  = (int*)carve((size_t)(N + 1) * 4);
    int*            CUR = (int*)carve((size_t)N * 4);
    int*            PRT = (int*)carve(1024 * 4);
    int*            COL = (int*)carve((size_t)E * 4);

    const int NB_E  = (E + 255) / 256;   // 2344
    const int NB_SC = (N + 511) / 512;   // 98
    const int NB_W  = (3 * 16384 + 3 * 2048 + 255) / 256;   // 216

    // single memset zeroes CNT(256B) + DEG
    (void)hipMemsetAsync(CNT, 0, 256 + (size_t)N * 4, stream);

    // ---- CSR build + weight prep (hist & wtwa fused, disjoint block ranges) ----
    k_hist_wtwa<<<NB_E + NB_W, 256, 0, stream>>>(dst, DEG, E, NB_E, W, attsrc, attdst, WT, WAT);
    k_scan1<<<NB_SC, 512, 0, stream>>>(DEG, INC, PRT, N);
    k_scan2<<<1, 128, 0, stream>>>(PRT, NB_SC);
    k_scan3<<<NB_SC, 512, 0, stream>>>(DEG, INC, PRT, RP, CUR, N, E);
    k_scatter<<<NB_E, 256, 0, stream>>>(src, dst, CUR, COL, E);

    for (int l = 0; l < 3; l++) {
        const float* Xf = (l == 0) ? x_in : XN;
        const float* st = (l == 0) ? nullptr : (STA + (l - 1) * 256);
        const float* gm = gamma + (l - 1) * 128;   // unused when l==0
        const float* bt = beta + (l - 1) * 128;
        k_gemm<<<(N + 63) / 64, 256, 0, stream>>>(Xf, st, gm, bt,
                                                  WT + l * 16384, WAT + l * 2048,
                                                  Hh, AS, AD, N, (l == 0) ? 0 : 1);
        k_agg<<<8 * 6250, 256, 0, stream>>>(RP, COL, AS, AD, Hh, XN, N);
        k_bnstats<<<256, 256, 0, stream>>>(XN, PAR, STA + l * 256, CNT + l, N);
    }
    k_bnapply<<<(N * 32 + 255) / 256, 256, 0, stream>>>(XN, STA + 2 * 256,
                                                        gamma + 2 * 128, beta + 2 * 128, out, N);
}

// Round 11
// 423.107 us; speedup vs baseline: 3.2873x; 1.7422x over previous
//
#include <hip/hip_runtime.h>
#include <hip/hip_bf16.h>

#define N_NODES 50000
#define N_EDGES 600000
#define HID 128
#define HEADS 8
#define OUTC 16
#define NEG_SLOPE 0.2f
#define BN_EPS 1e-5f

typedef __attribute__((ext_vector_type(8))) short short8;
typedef __attribute__((ext_vector_type(4))) float floatx4;

__device__ __forceinline__ float bf_lo(unsigned int v) { return __uint_as_float(v << 16); }
__device__ __forceinline__ float bf_hi(unsigned int v) { return __uint_as_float(v & 0xffff0000u); }

__device__ __forceinline__ short f2bfs(float v) {
    __hip_bfloat16 b = __float2bfloat16(v);
    return *reinterpret_cast<short*>(&b);
}
__device__ __forceinline__ unsigned int pack2(float lo, float hi) {
    return (unsigned int)(unsigned short)f2bfs(lo) | ((unsigned int)(unsigned short)f2bfs(hi) << 16);
}

// ---- hist (blocks < nb_e) + weight prep (blocks >= nb_e), independent work ----
__global__ void k_hist_wtwa(const int* __restrict__ dst, int* __restrict__ deg, int e,
                            int nb_e, const float* __restrict__ W,
                            const float* __restrict__ asrc, const float* __restrict__ adst,
                            __hip_bfloat16* __restrict__ Wt, __hip_bfloat16* __restrict__ WAT) {
    if (blockIdx.x < (unsigned)nb_e) {
        int i = blockIdx.x * 256 + threadIdx.x;
        if (i < e) atomicAdd(&deg[dst[i]], 1);
    } else {
        int i = (blockIdx.x - nb_e) * 256 + threadIdx.x;   // 55296 total
        if (i < 3 * 16384) {
            int l = i >> 14, r = i & 16383, n = r >> 7, k = r & 127;
            Wt[i] = __float2bfloat16(W[l * 16384 + k * 128 + n]);
        } else if (i < 3 * 16384 + 3 * 2048) {
            int q = i - 3 * 16384;
            int l = q >> 11, r = q & 2047, j = r >> 7, k = r & 127;
            const float* att = (j < 8) ? (asrc + l * 128 + j * 16) : (adst + l * 128 + (j - 8) * 16);
            const float* Wrow = W + l * 16384 + k * 128 + (j & 7) * 16;
            float sum = 0.f;
#pragma unroll
            for (int c = 0; c < 16; c++) sum += Wrow[c] * att[c];
            WAT[q] = __float2bfloat16(sum);
        }
    }
}

// ---------------- 3-kernel parallel scan (proven) ----------------
__global__ void k_scan1(const int* __restrict__ deg, int* __restrict__ incl,
                        int* __restrict__ partials, int n) {
    __shared__ int sh[512];
    int i = blockIdx.x * 512 + threadIdx.x;
    int v = (i < n) ? deg[i] : 0;
    sh[threadIdx.x] = v;
    __syncthreads();
    for (int off = 1; off < 512; off <<= 1) {
        int t = (threadIdx.x >= off) ? sh[threadIdx.x - off] : 0;
        __syncthreads();
        sh[threadIdx.x] += t;
        __syncthreads();
    }
    if (i < n) incl[i] = sh[threadIdx.x];
    if (threadIdx.x == 511) partials[blockIdx.x] = sh[511];
}

__global__ void k_scan2(int* __restrict__ partials, int nb) {
    __shared__ int sh[128];
    int v = (threadIdx.x < nb) ? partials[threadIdx.x] : 0;
    sh[threadIdx.x] = v;
    __syncthreads();
    for (int off = 1; off < 128; off <<= 1) {
        int t = (threadIdx.x >= off) ? sh[threadIdx.x - off] : 0;
        __syncthreads();
        sh[threadIdx.x] += t;
        __syncthreads();
    }
    if (threadIdx.x < nb) partials[threadIdx.x] = sh[threadIdx.x] - v;  // exclusive
}

__global__ void k_scan3(const int* __restrict__ deg, const int* __restrict__ incl,
                        const int* __restrict__ partials, int* __restrict__ row_ptr,
                        int* __restrict__ cursor, int n, int e_total) {
    int i = blockIdx.x * 512 + threadIdx.x;
    if (i < n) {
        int rp = incl[i] - deg[i] + partials[blockIdx.x];
        row_ptr[i] = rp;
        cursor[i] = rp;
    }
    if (i == 0) row_ptr[n] = e_total;
}

__global__ void k_scatter(const int* __restrict__ src, const int* __restrict__ dst,
                          int* __restrict__ cursor, int* __restrict__ col_src, int e) {
    int i = blockIdx.x * 256 + threadIdx.x;
    if (i < e) {
        int d = dst[i];
        int p = atomicAdd(&cursor[d], 1);
        col_src[p] = src[i];
    }
}

// ---- GEMM + fused BN/ELU on input + fused alpha via extra MFMA ----
// l==0: A from fp32 x_in (no BN). l>0: A from bf16 XB with BN+ELU applied.
__global__ __launch_bounds__(256) void k_gemm(const float* __restrict__ Xf,
                                              const unsigned short* __restrict__ Xb,
                                              const float* __restrict__ stats,
                                              const float* __restrict__ gamma,
                                              const float* __restrict__ beta,
                                              const __hip_bfloat16* __restrict__ Wt,
                                              const __hip_bfloat16* __restrict__ WAT,
                                              __hip_bfloat16* __restrict__ Hb,
                                              float* __restrict__ AS, float* __restrict__ AD,
                                              int n_nodes, int apply_bn) {
    __shared__ float s_scale[128], s_shift[128];
    if (apply_bn && threadIdx.x < 128) {
        int c = threadIdx.x;
        float invN = 1.0f / (float)N_NODES;
        float mu = stats[c] * invN;
        float var = stats[128 + c] * invN - mu * mu;
        float sc = rsqrtf(var + BN_EPS) * gamma[c];
        s_scale[c] = sc;
        s_shift[c] = beta[c] - mu * sc;
    }
    __syncthreads();

    int wave = threadIdx.x >> 6, lane = threadIdx.x & 63;
    int row0 = blockIdx.x * 64 + wave * 16;
    int m_lane = lane & 15, kq = lane >> 4;
    floatx4 acc[8] = {};
    floatx4 acc_a = {};
    const short* Ws = (const short*)Wt;
    const short* Was = (const short*)WAT;
    int r = row0 + m_lane;
    int rr = (r < n_nodes) ? r : 0;
    for (int c = 0; c < 4; c++) {
        short8 a;
        if (apply_bn) {
            uint4 u = *(const uint4*)(Xb + (size_t)rr * 128 + c * 32 + kq * 8);
            unsigned int uu[4] = {u.x, u.y, u.z, u.w};
            int ch0 = c * 32 + kq * 8;
#pragma unroll
            for (int j = 0; j < 4; j++) {
                float lo = bf_lo(uu[j]), hi = bf_hi(uu[j]);
                float v0 = fmaf(lo, s_scale[ch0 + 2 * j], s_shift[ch0 + 2 * j]);
                float v1 = fmaf(hi, s_scale[ch0 + 2 * j + 1], s_shift[ch0 + 2 * j + 1]);
                v0 = (v0 > 0.f) ? v0 : (__expf(v0) - 1.0f);
                v1 = (v1 > 0.f) ? v1 : (__expf(v1) - 1.0f);
                a[2 * j] = f2bfs(v0);
                a[2 * j + 1] = f2bfs(v1);
            }
        } else {
            const float4* xp = (const float4*)(Xf + (size_t)rr * 128 + c * 32 + kq * 8);
            float4 v0 = xp[0], v1 = xp[1];
            float vals[8] = {v0.x, v0.y, v0.z, v0.w, v1.x, v1.y, v1.z, v1.w};
#pragma unroll
            for (int j = 0; j < 8; j++) a[j] = f2bfs(vals[j]);
        }
        for (int t = 0; t < 8; t++) {
            short8 b = *(const short8*)(Ws + (t * 16 + m_lane) * 128 + c * 32 + kq * 8);
            acc[t] = __builtin_amdgcn_mfma_f32_16x16x32_bf16(a, b, acc[t], 0, 0, 0);
        }
        short8 bwa = *(const short8*)(Was + m_lane * 128 + c * 32 + kq * 8);
        acc_a = __builtin_amdgcn_mfma_f32_16x16x32_bf16(a, bwa, acc_a, 0, 0, 0);
    }
#pragma unroll
    for (int reg = 0; reg < 4; reg++) {
        int row = row0 + kq * 4 + reg;
        if (row >= n_nodes) continue;
#pragma unroll
        for (int t = 0; t < 8; t++)
            Hb[(size_t)row * 128 + t * 16 + m_lane] = __float2bfloat16(acc[t][reg]);
        float av = acc_a[reg];
        if (m_lane < 8) AS[row * 8 + m_lane] = av;
        else            AD[row * 8 + (m_lane - 8)] = av;
    }
}

// ---- segment softmax + aggregation (round-8 proven mapping), bf16 output ----
// one WAVE per node; lane = e_local(8) * 8 + head(8); 16 channels in registers.
__global__ __launch_bounds__(256) void k_agg(const int* __restrict__ RP,
                                             const int* __restrict__ COL,
                                             const float* __restrict__ AS,
                                             const float* __restrict__ AD,
                                             const __hip_bfloat16* __restrict__ Hb,
                                             unsigned short* __restrict__ XB, int n_nodes) {
    int wave = threadIdx.x >> 6, lane = threadIdx.x & 63;
    int n = blockIdx.x * 4 + wave;
    if (n >= n_nodes) return;
    int e_l = lane >> 3, h = lane & 7;
    int p0 = RP[n], p1 = RP[n + 1];
    float ad = AD[n * 8 + h];
    float z = 0.f;
    float acc[16];
#pragma unroll
    for (int c = 0; c < 16; c++) acc[c] = 0.f;
    const unsigned short* Hu = (const unsigned short*)Hb;
    for (int p = p0 + e_l; p < p1; p += 8) {
        int s = COL[p];
        float e = AS[s * 8 + h] + ad;
        e = (e > 0.f) ? e : NEG_SLOPE * e;
        float w = __expf(e);   // |e| << 80, safe without max-subtract
        z += w;
        const uint4* hp = (const uint4*)(Hu + (size_t)s * 128 + h * 16);
        uint4 h0 = hp[0];
        uint4 h1 = hp[1];
        unsigned int ww[8] = {h0.x, h0.y, h0.z, h0.w, h1.x, h1.y, h1.z, h1.w};
#pragma unroll
        for (int j = 0; j < 8; j++) {
            acc[2 * j]     += w * bf_lo(ww[j]);
            acc[2 * j + 1] += w * bf_hi(ww[j]);
        }
    }
#pragma unroll
    for (int off = 8; off < 64; off <<= 1) {
        z += __shfl_xor(z, off, 64);
#pragma unroll
        for (int c = 0; c < 16; c++) acc[c] += __shfl_xor(acc[c], off, 64);
    }
    if (e_l == 0) {
        float inv = 1.0f / (z + 1e-16f);
        unsigned int w[8];
#pragma unroll
        for (int j = 0; j < 8; j++)
            w[j] = pack2(acc[2 * j] * inv, acc[2 * j + 1] * inv);
        uint4* op = (uint4*)(XB + (size_t)n * 128 + h * 16);
        op[0] = make_uint4(w[0], w[1], w[2], w[3]);
        op[1] = make_uint4(w[4], w[5], w[6], w[7]);
    }
}

// ---- BN stats on bf16 XB: per-block partials + last-block reduce (grid=256) ----
__global__ __launch_bounds__(256) void k_bnstats(const unsigned short* __restrict__ x,
                                                 float* __restrict__ partials,
                                                 float* __restrict__ stats,
                                                 int* __restrict__ counter, int n_nodes) {
    int tid = threadIdx.x;
    int g8 = tid & 15, sub = tid >> 4;          // 16 row-groups per block
    int g = blockIdx.x * 16 + sub;              // 4096 row-groups total
    float s[8], q[8];
#pragma unroll
    for (int j = 0; j < 8; j++) { s[j] = 0.f; q[j] = 0.f; }
    for (int n = g; n < n_nodes; n += 4096) {
        uint4 u = *(const uint4*)(x + (size_t)n * 128 + g8 * 8);
        unsigned int uu[4] = {u.x, u.y, u.z, u.w};
#pragma unroll
        for (int j = 0; j < 4; j++) {
            float lo = bf_lo(uu[j]), hi = bf_hi(uu[j]);
            s[2 * j] += lo;     q[2 * j] += lo * lo;
            s[2 * j + 1] += hi; q[2 * j + 1] += hi * hi;
        }
    }
    __shared__ float ssum[16][128];
    __shared__ float ssq[16][128];
    int c = g8 * 8;
#pragma unroll
    for (int j = 0; j < 8; j++) { ssum[sub][c + j] = s[j]; ssq[sub][c + j] = q[j]; }
    __syncthreads();
    float total = 0.f;
    if (tid < 128) {
#pragma unroll
        for (int k = 0; k < 16; k++) total += ssum[k][tid];
    } else {
        int cc = tid - 128;
#pragma unroll
        for (int k = 0; k < 16; k++) total += ssq[k][cc];
    }
    partials[blockIdx.x * 256 + tid] = total;
    __threadfence();
    __shared__ int s_last;
    if (tid == 0) s_last = (atomicAdd(counter, 1) == 255) ? 1 : 0;
    __syncthreads();
    if (s_last) {
        float sum = 0.f;
#pragma unroll 8
        for (int b = 0; b < 256; b++) sum += partials[b * 256 + tid];
        stats[tid] = sum;
    }
}

// ---------------- final BN apply + ELU: bf16 XB -> fp32 out ----------------
__global__ void k_bnapply(const unsigned short* __restrict__ x, const float* __restrict__ stats,
                          const float* __restrict__ gamma, const float* __restrict__ beta,
                          float* __restrict__ outf, int n_nodes) {
    int i = blockIdx.x * 256 + threadIdx.x;   // each handles 8 channels
    if (i >= n_nodes * 16) return;
    uint4 u = *(const uint4*)(x + (size_t)i * 8);
    unsigned int uu[4] = {u.x, u.y, u.z, u.w};
    int c0 = (i * 8) & 127;
    float r[8];
#pragma unroll
    for (int j = 0; j < 4; j++) {
        r[2 * j] = bf_lo(uu[j]);
        r[2 * j + 1] = bf_hi(uu[j]);
    }
    float invN = 1.0f / (float)N_NODES;
#pragma unroll
    for (int j = 0; j < 8; j++) {
        int c = c0 + j;
        float mu = stats[c] * invN;
        float var = stats[128 + c] * invN - mu * mu;
        float sc = rsqrtf(var + BN_EPS) * gamma[c];
        float val = (r[j] - mu) * sc + beta[c];
        val = (val > 0.f) ? val : (__expf(val) - 1.0f);
        r[j] = val;
    }
    float4* op = (float4*)(outf + (size_t)i * 8);
    op[0] = make_float4(r[0], r[1], r[2], r[3]);
    op[1] = make_float4(r[4], r[5], r[6], r[7]);
}

extern "C" void kernel_launch(void* const* d_in, const int* in_sizes, int n_in,
                              void* d_out, int out_size, void* d_ws, size_t ws_size,
                              hipStream_t stream) {
    const float* x_in   = (const float*)d_in[0];
    const int*   eidx   = (const int*)d_in[1];
    const float* W      = (const float*)d_in[2];
    const float* attsrc = (const float*)d_in[3];
    const float* attdst = (const float*)d_in[4];
    // d_in[5] = bias — exactly cancelled by BatchNorm; unused.
    const float* gamma  = (const float*)d_in[6];
    const float* beta   = (const float*)d_in[7];
    float* out = (float*)d_out;

    const int N = N_NODES, E = N_EDGES;
    const int* src = eidx;
    const int* dst = eidx + E;

    char* base = (char*)d_ws;
    size_t off = 0;
    auto carve = [&](size_t bytes) -> char* {
        char* p = base + off;
        off += (bytes + 255) & ~(size_t)255;
        return p;
    };
    __hip_bfloat16* Hb  = (__hip_bfloat16*)carve((size_t)N * HID * 2);  // node-major bf16
    unsigned short* XB  = (unsigned short*)carve((size_t)N * HID * 2);  // bf16 inter-layer act
    float*          AS  = (float*)carve((size_t)N * HEADS * 4);
    float*          AD  = (float*)carve((size_t)N * HEADS * 4);
    __hip_bfloat16* WT  = (__hip_bfloat16*)carve((size_t)3 * HID * HID * 2);
    __hip_bfloat16* WAT = (__hip_bfloat16*)carve((size_t)3 * 16 * HID * 2);
    float*          STA = (float*)carve(3 * 256 * 4);
    float*          PAR = (float*)carve(256 * 256 * 4);
    int*            CNT = (int*)carve(256);                   // 3 counters (zeroed w/ DEG)
    int*            DEG = (int*)carve((size_t)N * 4);         // adjacent to CNT
    int*            INC = (int*)carve((size_t)N * 4);
    int*            RP  = (int*)carve((size_t)(N + 1) * 4);
    int*            CUR = (int*)carve((size_t)N * 4);
    int*            PRT = (int*)carve(1024 * 4);
    int*            COL = (int*)carve((size_t)E * 4);

    const int NB_E  = (E + 255) / 256;   // 2344
    const int NB_SC = (N + 511) / 512;   // 98
    const int NB_W  = (3 * 16384 + 3 * 2048 + 255) / 256;   // 216

    // single memset zeroes CNT(256B) + DEG
    (void)hipMemsetAsync(CNT, 0, 256 + (size_t)N * 4, stream);

    // ---- CSR build + weight prep (hist & wtwa fused, disjoint block ranges) ----
    k_hist_wtwa<<<NB_E + NB_W, 256, 0, stream>>>(dst, DEG, E, NB_E, W, attsrc, attdst, WT, WAT);
    k_scan1<<<NB_SC, 512, 0, stream>>>(DEG, INC, PRT, N);
    k_scan2<<<1, 128, 0, stream>>>(PRT, NB_SC);
    k_scan3<<<NB_SC, 512, 0, stream>>>(DEG, INC, PRT, RP, CUR, N, E);
    k_scatter<<<NB_E, 256, 0, stream>>>(src, dst, CUR, COL, E);

    for (int l = 0; l < 3; l++) {
        const float* st = (l == 0) ? nullptr : (STA + (l - 1) * 256);
        const float* gm = gamma + (l - 1) * 128;   // unused when l==0
        const float* bt = beta + (l - 1) * 128;
        k_gemm<<<(N + 63) / 64, 256, 0, stream>>>(x_in, XB, st, gm, bt,
                                                  WT + l * 16384, WAT + l * 2048,
                                                  Hb, AS, AD, N, (l == 0) ? 0 : 1);
        k_agg<<<(N + 3) / 4, 256, 0, stream>>>(RP, COL, AS, AD, Hb, XB, N);
        k_bnstats<<<256, 256, 0, stream>>>(XB, PAR, STA + l * 256, CNT + l, N);
    }
    k_bnapply<<<(N * 16 + 255) / 256, 256, 0, stream>>>(XB, STA + 2 * 256,
                                                        gamma + 2 * 128, beta + 2 * 128, out, N);
}